// Round 1
// baseline (10300.061 us; speedup 1.0000x reference)
//
#include <hip/hip_runtime.h>
#include <cstdint>
#include <cstddef>

// ---- problem constants ----
#define BB    2048
#define LL    200
#define DD    128
#define GR    8      // batch rows per block in scan kernels
#define MR    8      // batch rows per block in MLP

__device__ __forceinline__ float sigmf(float x) { return 1.f / (1.f + __expf(-x)); }
__device__ __forceinline__ float dot4(float4 a, float4 b) {
    return a.x * b.x + a.y * b.y + a.z * b.z + a.w * b.w;
}
__device__ __forceinline__ float4 ld4(const float* p) { return *(const float4*)p; }
__device__ __forceinline__ void st4(float* p, float4 v) { *(float4*)p = v; }

// ---- K0: transpose small weight matrices (dst[k*rows + j] = src[j*cols + k]) ----
__global__ void transpose_kernel(const float* __restrict__ src, float* __restrict__ dst,
                                 int rows, int cols) {
    int k = blockIdx.x;  // 0..cols-1
    for (int j = threadIdx.x; j < rows; j += blockDim.x)
        dst[(size_t)k * rows + j] = src[(size_t)j * cols + k];
}

// ---- K1: target = item_table[item_id] @ proj_W^T   (B,128) ----
__global__ __launch_bounds__(128) void target_kernel(
    const int* __restrict__ item_id, const float* __restrict__ item_table,
    const float* __restrict__ projW, float* __restrict__ target) {
    __shared__ float ie[64];
    int b = blockIdx.x, d = threadIdx.x;
    if (d < 64) ie[d] = item_table[(size_t)item_id[b] * 64 + d];
    __syncthreads();
    float acc = 0.f;
    const float* w = projW + (size_t)d * 64;
#pragma unroll
    for (int k = 0; k < 64; k += 4) acc += dot4(ld4(&ie[k]), ld4(w + k));
    target[(size_t)b * 128 + d] = acc;
}

// ---- K2: GRU scan over L, fused gi projection + attention scores ----
// 256 blocks x 256 threads; block owns GR=8 batch rows; thread = (d = tid&127, rr = tid>>7)
// handling rows rr*4..rr*4+3 and gate columns {d, 128+d, 256+d}.
__global__ __launch_bounds__(256) void gru_kernel(
    const int* __restrict__ hseq, const float* __restrict__ hist_table,
    const float* __restrict__ Wi, const float* __restrict__ Wh,
    const float* __restrict__ bi, const float* __restrict__ bh,
    const float* __restrict__ target,
    float* __restrict__ h_states, float* __restrict__ scores) {
    __shared__ float Wbuf[384 * 36];   // one 384x32 k-chunk, stride 36 (16B aligned)
    __shared__ float xs[GR][132];
    __shared__ float hs[GR][132];
    __shared__ float tg[GR][132];
    __shared__ int sidx[GR];
    const int tid = threadIdx.x;
    const int d = tid & 127;
    const int rr = tid >> 7;  // 0..1
    const int b0 = blockIdx.x * GR;
    const float bir = bi[d], biz = bi[128 + d], bin = bi[256 + d];
    const float bhr = bh[d], bhz = bh[128 + d], bhn = bh[256 + d];
    for (int i = tid; i < GR * 128; i += 256) {
        int r = i >> 7, k = i & 127;
        tg[r][k] = target[(size_t)(b0 + r) * 128 + k];
        hs[r][k] = 0.f;
    }
    __syncthreads();
    for (int tt = 0; tt < LL; ++tt) {
        if (tid < GR) sidx[tid] = hseq[(size_t)(b0 + tid) * LL + tt];
        __syncthreads();
        {   // gather hist_emb rows for this step (8 rows x 128 floats)
            int r = tid >> 5, kk = (tid & 31) << 2;
            st4(&xs[r][kk], ld4(hist_table + (size_t)sidx[r] * 128 + kk));
        }
        float ai0[4] = {0, 0, 0, 0}, ai1[4] = {0, 0, 0, 0}, ai2[4] = {0, 0, 0, 0};
        float ah0[4] = {0, 0, 0, 0}, ah1[4] = {0, 0, 0, 0}, ah2[4] = {0, 0, 0, 0};
        // ---- gi = x @ Wi^T, chunked over k ----
        for (int kc = 0; kc < 4; ++kc) {
            __syncthreads();  // Wbuf overwrite safety (also covers xs gather completion)
            for (int g = tid; g < 3072; g += 256) {
                int col = g >> 3, kk = (g & 7) << 2;
                st4(&Wbuf[col * 36 + kk], ld4(Wi + (size_t)col * 128 + kc * 32 + kk));
            }
            __syncthreads();
#pragma unroll
            for (int k4 = 0; k4 < 8; ++k4) {
                int kk = k4 << 2;
                float4 w0 = ld4(&Wbuf[d * 36 + kk]);
                float4 w1 = ld4(&Wbuf[(128 + d) * 36 + kk]);
                float4 w2 = ld4(&Wbuf[(256 + d) * 36 + kk]);
#pragma unroll
                for (int j = 0; j < 4; ++j) {
                    float4 xv = ld4(&xs[rr * 4 + j][kc * 32 + kk]);
                    ai0[j] += dot4(xv, w0);
                    ai1[j] += dot4(xv, w1);
                    ai2[j] += dot4(xv, w2);
                }
            }
        }
        // ---- gh = h @ Wh^T, chunked over k ----
        for (int kc = 0; kc < 4; ++kc) {
            __syncthreads();
            for (int g = tid; g < 3072; g += 256) {
                int col = g >> 3, kk = (g & 7) << 2;
                st4(&Wbuf[col * 36 + kk], ld4(Wh + (size_t)col * 128 + kc * 32 + kk));
            }
            __syncthreads();
#pragma unroll
            for (int k4 = 0; k4 < 8; ++k4) {
                int kk = k4 << 2;
                float4 w0 = ld4(&Wbuf[d * 36 + kk]);
                float4 w1 = ld4(&Wbuf[(128 + d) * 36 + kk]);
                float4 w2 = ld4(&Wbuf[(256 + d) * 36 + kk]);
#pragma unroll
                for (int j = 0; j < 4; ++j) {
                    float4 hv = ld4(&hs[rr * 4 + j][kc * 32 + kk]);
                    ah0[j] += dot4(hv, w0);
                    ah1[j] += dot4(hv, w1);
                    ah2[j] += dot4(hv, w2);
                }
            }
        }
        __syncthreads();  // all hs reads complete before gate writes
#pragma unroll
        for (int j = 0; j < 4; ++j) {
            int r = rr * 4 + j;
            float rg = sigmf(ai0[j] + bir + ah0[j] + bhr);
            float z = sigmf(ai1[j] + biz + ah1[j] + bhz);
            float n = tanhf(ai2[j] + bin + rg * (ah2[j] + bhn));
            float hold = hs[r][d];
            float hnew = (1.f - z) * n + z * hold;
            hs[r][d] = hnew;
            h_states[((size_t)(b0 + r) * LL + tt) * 128 + d] = hnew;
        }
        __syncthreads();  // hs ready for score reduction
        {   // attention scores: score[r] = (h . target[r]) / sqrt(128)
            int r = tid >> 5, j = tid & 31;
            float p = 0.f;
#pragma unroll
            for (int m = 0; m < 4; ++m) p += hs[r][j + 32 * m] * tg[r][j + 32 * m];
            p += __shfl_xor(p, 16);
            p += __shfl_xor(p, 8);
            p += __shfl_xor(p, 4);
            p += __shfl_xor(p, 2);
            p += __shfl_xor(p, 1);
            if (j == 0) scores[(size_t)(b0 + r) * LL + tt] = p * 0.08838834764831845f;
        }
        // loop-top __syncthreads (after sidx write) separates score reads from next writes
    }
}

// ---- K3: masked softmax over L=200 per batch row (one wave per row) ----
__global__ __launch_bounds__(256) void softmax_kernel(
    const float* __restrict__ scores, const int* __restrict__ hseq,
    float* __restrict__ attn) {
    int w = threadIdx.x >> 6;
    int lane = threadIdx.x & 63;
    int b = blockIdx.x * 4 + w;
    float v[4];
#pragma unroll
    for (int m = 0; m < 4; ++m) {
        int t = lane + 64 * m;
        if (t < LL) {
            float s = scores[(size_t)b * LL + t];
            v[m] = (hseq[(size_t)b * LL + t] > 0) ? s : -1e9f;
        } else
            v[m] = -3.0e38f;
    }
    float mx = fmaxf(fmaxf(v[0], v[1]), fmaxf(v[2], v[3]));
    for (int off = 1; off < 64; off <<= 1) mx = fmaxf(mx, __shfl_xor(mx, off));
    float s = 0.f;
#pragma unroll
    for (int m = 0; m < 4; ++m) {
        int t = lane + 64 * m;
        v[m] = (t < LL) ? __expf(v[m] - mx) : 0.f;
        s += v[m];
    }
    for (int off = 1; off < 64; off <<= 1) s += __shfl_xor(s, off);
    float inv = 1.f / s;
#pragma unroll
    for (int m = 0; m < 4; ++m) {
        int t = lane + 64 * m;
        if (t < LL) attn[(size_t)b * LL + t] = v[m] * inv;
    }
}

// ---- K4: AUGRU scan ----
// Same decomposition as GRU: 256 blocks x 256 threads, GR=8 rows/block.
__global__ __launch_bounds__(256) void augru_kernel(
    const float* __restrict__ h_states, const float* __restrict__ attn,
    const int* __restrict__ hseq,
    const float* __restrict__ Wr, const float* __restrict__ Wu,
    const float* __restrict__ Wht,
    const float* __restrict__ br, const float* __restrict__ bu,
    const float* __restrict__ bh, float* __restrict__ evolved) {
    __shared__ float Wbuf[17408];  // 69632 B, reused across phases
    __shared__ float xs[GR][132];
    __shared__ float hs[GR][132];
    __shared__ float rh[GR][132];
    __shared__ float se[GR];
    __shared__ float sm[GR];
    const int tid = threadIdx.x;
    const int d = tid & 127;
    const int rr = tid >> 7;
    const int b0 = blockIdx.x * GR;
    const float brr = br[d], bur = bu[d], bhr = bh[d];
    for (int i = tid; i < GR * 128; i += 256) hs[i >> 7][i & 127] = 0.f;
    __syncthreads();
    for (int tt = 0; tt < LL; ++tt) {
        if (tid < GR) {
            se[tid] = attn[(size_t)(b0 + tid) * LL + tt];
            sm[tid] = (hseq[(size_t)(b0 + tid) * LL + tt] > 0) ? 1.f : 0.f;
        }
        __syncthreads();
        {   // x_t = h_states[:, tt, :]
            int r = tid >> 5, kk = (tid & 31) << 2;
            st4(&xs[r][kk], ld4(h_states + ((size_t)(b0 + r) * LL + tt) * 128 + kk));
        }
        float ar[4] = {0, 0, 0, 0}, au_[4] = {0, 0, 0, 0};
        float ax[4] = {0, 0, 0, 0}, ahh[4] = {0, 0, 0, 0};
        // ---- X phase: k 0..127 of Wr,Wu,Wh vs x_t ----
        for (int kc = 0; kc < 4; ++kc) {
            __syncthreads();
            for (int g = tid; g < 3072; g += 256) {
                int m = g >> 10, rem = g & 1023;
                int col = rem >> 3, kk = (rem & 7) << 2;
                const float* src = (m == 0 ? Wr : (m == 1 ? Wu : Wht));
                st4(&Wbuf[m * 4608 + col * 36 + kk],
                    ld4(src + (size_t)col * 256 + kc * 32 + kk));
            }
            __syncthreads();
#pragma unroll
            for (int k4 = 0; k4 < 8; ++k4) {
                int kk = k4 << 2;
                float4 w0 = ld4(&Wbuf[d * 36 + kk]);
                float4 w1 = ld4(&Wbuf[4608 + d * 36 + kk]);
                float4 w2 = ld4(&Wbuf[9216 + d * 36 + kk]);
#pragma unroll
                for (int j = 0; j < 4; ++j) {
                    float4 xv = ld4(&xs[rr * 4 + j][kc * 32 + kk]);
                    ar[j] += dot4(xv, w0);
                    au_[j] += dot4(xv, w1);
                    ax[j] += dot4(xv, w2);
                }
            }
        }
        // ---- H phase: k 128..255 of Wr,Wu vs h ----
        for (int hc = 0; hc < 2; ++hc) {
            __syncthreads();
            for (int g = tid; g < 4096; g += 256) {
                int m = g >> 11, rem = g & 2047;
                int col = rem >> 4, kk = (rem & 15) << 2;
                const float* src = (m == 0 ? Wr : Wu);
                st4(&Wbuf[m * 8704 + col * 68 + kk],
                    ld4(src + (size_t)col * 256 + 128 + hc * 64 + kk));
            }
            __syncthreads();
#pragma unroll
            for (int k4 = 0; k4 < 16; ++k4) {
                int kk = k4 << 2;
                float4 w0 = ld4(&Wbuf[d * 68 + kk]);
                float4 w1 = ld4(&Wbuf[8704 + d * 68 + kk]);
#pragma unroll
                for (int j = 0; j < 4; ++j) {
                    float4 hv = ld4(&hs[rr * 4 + j][hc * 64 + kk]);
                    ar[j] += dot4(hv, w0);
                    au_[j] += dot4(hv, w1);
                }
            }
        }
        __syncthreads();  // Wbuf + hs reads complete
        // r gate -> rh = r * h (old h)
#pragma unroll
        for (int j = 0; j < 4; ++j) {
            int r = rr * 4 + j;
            float rv = sigmf(ar[j] + brr);
            rh[r][d] = rv * hs[r][d];
        }
        // stage Wh h-part (full 128 k)
        for (int g = tid; g < 4096; g += 256) {
            int col = g >> 5, kk = (g & 31) << 2;
            st4(&Wbuf[col * 132 + kk], ld4(Wht + (size_t)col * 256 + 128 + kk));
        }
        __syncthreads();
#pragma unroll
        for (int k4 = 0; k4 < 32; ++k4) {
            int kk = k4 << 2;
            float4 w0 = ld4(&Wbuf[d * 132 + kk]);
#pragma unroll
            for (int j = 0; j < 4; ++j) {
                float4 rv = ld4(&rh[rr * 4 + j][kk]);
                ahh[j] += dot4(rv, w0);
            }
        }
        // gates + masked update (each thread touches only its own hs elements)
#pragma unroll
        for (int j = 0; j < 4; ++j) {
            int r = rr * 4 + j;
            float u = sigmf(au_[j] + bur);
            float up = se[r] * u;
            float ht = tanhf(ax[j] + ahh[j] + bhr);
            float hold = hs[r][d];
            float hnew = (1.f - up) * hold + up * ht;
            hs[r][d] = sm[r] > 0.5f ? hnew : hold;
        }
        __syncthreads();  // protect se/sm rewrite + rh reads at next step
    }
#pragma unroll
    for (int j = 0; j < 4; ++j) {
        int r = rr * 4 + j;
        evolved[(size_t)(b0 + r) * 128 + d] = hs[r][d];
    }
}

// ---- K5: feature concat + 3-layer MLP + sigmoid ----
__global__ __launch_bounds__(256) void mlp_kernel(
    const int* __restrict__ user_id, const int* __restrict__ item_id,
    const int* __restrict__ item_cat, const int* __restrict__ item_dur,
    const float* __restrict__ user_dense, const float* __restrict__ item_dense,
    const float* __restrict__ user_table, const float* __restrict__ item_table,
    const float* __restrict__ cat_table, const float* __restrict__ dur_table,
    const float* __restrict__ evolved,
    const float* __restrict__ W1t, const float* __restrict__ b1,
    const float* __restrict__ W2t, const float* __restrict__ b2,
    const float* __restrict__ W3, const float* __restrict__ b3,
    float* __restrict__ out) {
    __shared__ float Xs[MR][332];
    __shared__ float h1s[MR][256];
    __shared__ float h2s[MR][128];
    __shared__ int ids[4][MR];
    const int tid = threadIdx.x;
    const int b0 = blockIdx.x * MR;
    if (tid < MR) {
        ids[0][tid] = user_id[b0 + tid];
        ids[1][tid] = item_id[b0 + tid];
        ids[2][tid] = item_cat[b0 + tid];
        ids[3][tid] = item_dur[b0 + tid];
    }
    __syncthreads();
    for (int i = tid; i < MR * 332; i += 256) {
        int r = i / 332, c = i % 332;
        int b = b0 + r;
        float v;
        if (c < 64) v = user_table[(size_t)ids[0][r] * 64 + c];
        else if (c < 128) v = item_table[(size_t)ids[1][r] * 64 + (c - 64)];
        else if (c < 160) v = cat_table[(size_t)ids[2][r] * 32 + (c - 128)];
        else if (c < 176) v = dur_table[(size_t)ids[3][r] * 16 + (c - 160)];
        else if (c < 201) v = user_dense[(size_t)b * 25 + (c - 176)];
        else if (c < 204) v = item_dense[(size_t)b * 3 + (c - 201)];
        else v = evolved[(size_t)b * 128 + (c - 204)];
        Xs[r][c] = v;
    }
    __syncthreads();
    {   // h1 = relu(X @ W1^T + b1): thread = output col
        float acc[MR] = {0, 0, 0, 0, 0, 0, 0, 0};
        for (int k = 0; k < 332; ++k) {
            float w = W1t[(size_t)k * 256 + tid];
#pragma unroll
            for (int r = 0; r < MR; ++r) acc[r] += Xs[r][k] * w;
        }
        float bb = b1[tid];
#pragma unroll
        for (int r = 0; r < MR; ++r) h1s[r][tid] = fmaxf(acc[r] + bb, 0.f);
    }
    __syncthreads();
    if (tid < 128) {  // h2 = relu(h1 @ W2^T + b2)
        float acc[MR] = {0, 0, 0, 0, 0, 0, 0, 0};
        for (int k = 0; k < 256; ++k) {
            float w = W2t[(size_t)k * 128 + tid];
#pragma unroll
            for (int r = 0; r < MR; ++r) acc[r] += h1s[r][k] * w;
        }
        float bb = b2[tid];
#pragma unroll
        for (int r = 0; r < MR; ++r) h2s[r][tid] = fmaxf(acc[r] + bb, 0.f);
    }
    __syncthreads();
    {   // logit + sigmoid
        int r = tid >> 5, j = tid & 31;
        float p = 0.f;
#pragma unroll
        for (int m = 0; m < 4; ++m) p += h2s[r][j + 32 * m] * W3[j + 32 * m];
        p += __shfl_xor(p, 16);
        p += __shfl_xor(p, 8);
        p += __shfl_xor(p, 4);
        p += __shfl_xor(p, 2);
        p += __shfl_xor(p, 1);
        if (j == 0) out[b0 + r] = 1.f / (1.f + __expf(-(p + b3[0])));
    }
}

extern "C" void kernel_launch(void* const* d_in, const int* in_sizes, int n_in,
                              void* d_out, int out_size, void* d_ws, size_t ws_size,
                              hipStream_t stream) {
    const int* user_id = (const int*)d_in[0];
    const int* item_id = (const int*)d_in[1];
    const int* item_cat = (const int*)d_in[2];
    const int* item_dur = (const int*)d_in[3];
    const int* hseq = (const int*)d_in[4];
    const float* user_dense = (const float*)d_in[5];
    const float* item_dense = (const float*)d_in[6];
    const float* user_table = (const float*)d_in[7];
    const float* item_table = (const float*)d_in[8];
    const float* cat_table = (const float*)d_in[9];
    const float* dur_table = (const float*)d_in[10];
    const float* hist_table = (const float*)d_in[11];
    const float* projW = (const float*)d_in[12];
    const float* gWi = (const float*)d_in[13];
    const float* gWh = (const float*)d_in[14];
    const float* gbi = (const float*)d_in[15];
    const float* gbh = (const float*)d_in[16];
    const float* aWr = (const float*)d_in[17];
    const float* abr = (const float*)d_in[18];
    const float* aWu = (const float*)d_in[19];
    const float* abu = (const float*)d_in[20];
    const float* aWh = (const float*)d_in[21];
    const float* abh = (const float*)d_in[22];
    const float* mW1 = (const float*)d_in[23];
    const float* mb1 = (const float*)d_in[24];
    const float* mW2 = (const float*)d_in[25];
    const float* mb2 = (const float*)d_in[26];
    const float* mW3 = (const float*)d_in[27];
    const float* mb3 = (const float*)d_in[28];
    float* out = (float*)d_out;

    // workspace layout (floats); total ~215.6 MB
    float* ws = (float*)d_ws;
    float* target = ws;                         // 2048*128      = 262144
    float* h_states = target + 262144;          // 2048*200*128  = 52428800
    float* scores = h_states + 52428800;        // 2048*200      = 409600
    float* attn = scores + 409600;              // 409600
    float* evolved = attn + 409600;             // 262144
    float* W1t = evolved + 262144;              // 332*256       = 84992
    float* W2t = W1t + 84992;                   // 256*128       = 32768

    hipLaunchKernelGGL(transpose_kernel, dim3(332), dim3(256), 0, stream, mW1, W1t, 256, 332);
    hipLaunchKernelGGL(transpose_kernel, dim3(256), dim3(128), 0, stream, mW2, W2t, 128, 256);
    hipLaunchKernelGGL(target_kernel, dim3(2048), dim3(128), 0, stream,
                       item_id, item_table, projW, target);
    hipLaunchKernelGGL(gru_kernel, dim3(BB / GR), dim3(256), 0, stream,
                       hseq, hist_table, gWi, gWh, gbi, gbh, target, h_states, scores);
    hipLaunchKernelGGL(softmax_kernel, dim3(BB / 4), dim3(256), 0, stream, scores, hseq, attn);
    hipLaunchKernelGGL(augru_kernel, dim3(BB / GR), dim3(256), 0, stream,
                       h_states, attn, hseq, aWr, aWu, aWh, abr, abu, abh, evolved);
    hipLaunchKernelGGL(mlp_kernel, dim3(BB / MR), dim3(256), 0, stream,
                       user_id, item_id, item_cat, item_dur, user_dense, item_dense,
                       user_table, item_table, cat_table, dur_table, evolved,
                       W1t, mb1, W2t, mb2, mW3, mb3, out);
}

// Round 2
// 830.528 us; speedup vs baseline: 12.4018x; 12.4018x over previous
//
#include <hip/hip_runtime.h>
#include <cstdint>
#include <cstddef>

// ---- problem constants ----
#define BB    2048
#define LL    200
#define GR    8      // batch rows per block in scan kernels
#define MR    8      // batch rows per block in MLP

typedef __attribute__((ext_vector_type(4))) float f32x4;
typedef __attribute__((ext_vector_type(8))) short s16x8;

__device__ __forceinline__ float sigmf(float x) { return 1.f / (1.f + __expf(-x)); }
__device__ __forceinline__ float dot4(float4 a, float4 b) {
    return a.x * b.x + a.y * b.y + a.z * b.z + a.w * b.w;
}
__device__ __forceinline__ float4 ld4(const float* p) { return *(const float4*)p; }
__device__ __forceinline__ void st4(float* p, float4 v) { *(float4*)p = v; }

__device__ __forceinline__ unsigned short f2bf(float f) {  // RNE
    union { float f; unsigned u; } v; v.f = f;
    unsigned r = (v.u + 0x7FFFu + ((v.u >> 16) & 1u)) >> 16;
    return (unsigned short)r;
}
// pack 8 consecutive fp32 (16B-aligned) -> bf16x8 frag
__device__ __forceinline__ s16x8 pack8g(const float* p) {
    float4 a = ld4(p), b = ld4(p + 4);
    s16x8 o;
    o[0] = (short)f2bf(a.x); o[1] = (short)f2bf(a.y);
    o[2] = (short)f2bf(a.z); o[3] = (short)f2bf(a.w);
    o[4] = (short)f2bf(b.x); o[5] = (short)f2bf(b.y);
    o[6] = (short)f2bf(b.z); o[7] = (short)f2bf(b.w);
    return o;
}
#define MFMA(a, b, c) __builtin_amdgcn_mfma_f32_16x16x32_bf16((a), (b), (c), 0, 0, 0)

// ---- K0: transpose small weight matrices (dst[k*rows + j] = src[j*cols + k]) ----
__global__ void transpose_kernel(const float* __restrict__ src, float* __restrict__ dst,
                                 int rows, int cols) {
    int k = blockIdx.x;
    for (int j = threadIdx.x; j < rows; j += blockDim.x)
        dst[(size_t)k * rows + j] = src[(size_t)j * cols + k];
}

// ---- K1: target = item_table[item_id] @ proj_W^T   (B,128) ----
__global__ __launch_bounds__(128) void target_kernel(
    const int* __restrict__ item_id, const float* __restrict__ item_table,
    const float* __restrict__ projW, float* __restrict__ target) {
    __shared__ float ie[64];
    int b = blockIdx.x, d = threadIdx.x;
    if (d < 64) ie[d] = item_table[(size_t)item_id[b] * 64 + d];
    __syncthreads();
    float acc = 0.f;
    const float* w = projW + (size_t)d * 64;
#pragma unroll
    for (int k = 0; k < 64; k += 4) acc += dot4(ld4(&ie[k]), ld4(w + k));
    target[(size_t)b * 128 + d] = acc;
}

// ---- K2: GRU scan, weights-stationary MFMA ----
// 256 blocks x 512 threads (8 waves). Block owns GR=8 batch rows (padded to 16
// for MFMA). Wave w owns gate-columns [48w, 48w+48) of the 384-col space
// (r:0-127, z:128-255, n:256-383); its Wi/Wh slices live in VGPRs as bf16
// B-fragments for all 200 steps. Per step: pack x_t/h A-frags -> 24 MFMA/wave
// -> gi/gh to LDS -> fp32 gates -> h + bf16 h_states + attention score.
__global__ __launch_bounds__(512, 2) void gru_v2(
    const int* __restrict__ hseq, const float* __restrict__ hist,
    const float* __restrict__ Wi, const float* __restrict__ Wh,
    const float* __restrict__ bi, const float* __restrict__ bh,
    const float* __restrict__ target,
    unsigned short* __restrict__ h_bf, float* __restrict__ scores) {
    __shared__ alignas(16) unsigned short xf[2048];  // A-frags x: [kc][lane][8]
    __shared__ alignas(16) unsigned short hf[2048];  // A-frags h
    __shared__ float gib[8 * 388];
    __shared__ float ghb[8 * 388];
    __shared__ float hs[8 * 132];
    const int tid = threadIdx.x;
    const int w = tid >> 6;
    const int lane = tid & 63;
    const int b0 = blockIdx.x * GR;
    const int grow = tid >> 6;       // gate-phase row (== wave id)
    const int dd = tid & 63;         // gate-phase d; handles dd and dd+64
    // biases + target (per-thread constants)
    const float bi_r0 = bi[dd],       bi_r1 = bi[dd + 64];
    const float bi_z0 = bi[128 + dd], bi_z1 = bi[192 + dd];
    const float bi_n0 = bi[256 + dd], bi_n1 = bi[320 + dd];
    const float bh_r0 = bh[dd],       bh_r1 = bh[dd + 64];
    const float bh_z0 = bh[128 + dd], bh_z1 = bh[192 + dd];
    const float bh_n0 = bh[256 + dd], bh_n1 = bh[320 + dd];
    const float tg0 = target[(size_t)(b0 + grow) * 128 + dd];
    const float tg1 = target[(size_t)(b0 + grow) * 128 + dd + 64];
    // persistent weight fragments: B[k][c]=W[c][k]; lane holds c=base+(l&15),
    // k = kc*32 + (l>>4)*8 + j
    s16x8 wi[3][4], wh[3][4];
#pragma unroll
    for (int ct = 0; ct < 3; ++ct)
#pragma unroll
        for (int kc = 0; kc < 4; ++kc) {
            int r = w * 48 + ct * 16 + (lane & 15);
            int ko = kc * 32 + (lane >> 4) * 8;
            wi[ct][kc] = pack8g(Wi + (size_t)r * 128 + ko);
            wh[ct][kc] = pack8g(Wh + (size_t)r * 128 + ko);
        }
    for (int i = tid; i < 2048; i += 512) { xf[i] = 0; hf[i] = 0; }
    for (int i = tid; i < 8 * 132; i += 512) hs[i] = 0.f;
    __syncthreads();
    // pack-phase coords
    const int pkc = (tid & 255) >> 6;
    const int plane = tid & 63;
    const int prow = plane & 15;
    const int pko = pkc * 32 + ((plane >> 4) & 3) * 8;
    for (int tt = 0; tt < LL; ++tt) {
        // ---- P1: pack A-frags (x_t by waves 0-3, h by waves 4-7) ----
        if (tid < 256) {
            if (prow < GR) {
                int idx = hseq[(size_t)(b0 + prow) * LL + tt];
                *(s16x8*)&xf[(pkc * 64 + plane) * 8] =
                    pack8g(hist + (size_t)idx * 128 + pko);
            }
        } else {
            if (prow < GR)
                *(s16x8*)&hf[(pkc * 64 + plane) * 8] = pack8g(&hs[prow * 132 + pko]);
        }
        __syncthreads();
        // ---- P2: MFMA ----
        {
            f32x4 z = {0.f, 0.f, 0.f, 0.f};
            f32x4 ai0 = z, ai1 = z, ai2 = z, ah0 = z, ah1 = z, ah2 = z;
#pragma unroll
            for (int kc = 0; kc < 4; ++kc) {
                s16x8 xa = *(const s16x8*)&xf[(kc * 64 + lane) * 8];
                s16x8 ha = *(const s16x8*)&hf[(kc * 64 + lane) * 8];
                ai0 = MFMA(xa, wi[0][kc], ai0); ah0 = MFMA(ha, wh[0][kc], ah0);
                ai1 = MFMA(xa, wi[1][kc], ai1); ah1 = MFMA(ha, wh[1][kc], ah1);
                ai2 = MFMA(xa, wi[2][kc], ai2); ah2 = MFMA(ha, wh[2][kc], ah2);
            }
            if (lane < 32) {  // rows 0..7 only
                int rb = (lane >> 4) * 4;
                int cb = w * 48 + (lane & 15);
#pragma unroll
                for (int q = 0; q < 4; ++q) {
                    gib[(rb + q) * 388 + cb]      = ai0[q];
                    gib[(rb + q) * 388 + cb + 16] = ai1[q];
                    gib[(rb + q) * 388 + cb + 32] = ai2[q];
                    ghb[(rb + q) * 388 + cb]      = ah0[q];
                    ghb[(rb + q) * 388 + cb + 16] = ah1[q];
                    ghb[(rb + q) * 388 + cb + 32] = ah2[q];
                }
            }
        }
        __syncthreads();
        // ---- P3: fp32 gates + h update + score ----
        {
            const float* gi = &gib[grow * 388];
            const float* gh = &ghb[grow * 388];
            float r0 = sigmf(gi[dd] + bi_r0 + gh[dd] + bh_r0);
            float z0 = sigmf(gi[128 + dd] + bi_z0 + gh[128 + dd] + bh_z0);
            float n0 = tanhf(gi[256 + dd] + bi_n0 + r0 * (gh[256 + dd] + bh_n0));
            float r1 = sigmf(gi[64 + dd] + bi_r1 + gh[64 + dd] + bh_r1);
            float z1 = sigmf(gi[192 + dd] + bi_z1 + gh[192 + dd] + bh_z1);
            float n1 = tanhf(gi[320 + dd] + bi_n1 + r1 * (gh[320 + dd] + bh_n1));
            float ho0 = hs[grow * 132 + dd];
            float ho1 = hs[grow * 132 + dd + 64];
            float hn0 = (1.f - z0) * n0 + z0 * ho0;
            float hn1 = (1.f - z1) * n1 + z1 * ho1;
            hs[grow * 132 + dd] = hn0;
            hs[grow * 132 + dd + 64] = hn1;
            size_t hbase = ((size_t)(b0 + grow) * LL + tt) * 128;
            h_bf[hbase + dd] = f2bf(hn0);
            h_bf[hbase + dd + 64] = f2bf(hn1);
            float p = hn0 * tg0 + hn1 * tg1;
            p += __shfl_xor(p, 32);
            p += __shfl_xor(p, 16);
            p += __shfl_xor(p, 8);
            p += __shfl_xor(p, 4);
            p += __shfl_xor(p, 2);
            p += __shfl_xor(p, 1);
            if (dd == 0) scores[(size_t)(b0 + grow) * LL + tt] = p * 0.08838834764831845f;
        }
        __syncthreads();
    }
}

// ---- K3: masked softmax over L=200 per batch row (one wave per row) ----
__global__ __launch_bounds__(256) void softmax_kernel(
    const float* __restrict__ scores, const int* __restrict__ hseq,
    float* __restrict__ attn) {
    int w = threadIdx.x >> 6;
    int lane = threadIdx.x & 63;
    int b = blockIdx.x * 4 + w;
    float v[4];
#pragma unroll
    for (int m = 0; m < 4; ++m) {
        int t = lane + 64 * m;
        if (t < LL) {
            float s = scores[(size_t)b * LL + t];
            v[m] = (hseq[(size_t)b * LL + t] > 0) ? s : -1e9f;
        } else
            v[m] = -3.0e38f;
    }
    float mx = fmaxf(fmaxf(v[0], v[1]), fmaxf(v[2], v[3]));
    for (int off = 1; off < 64; off <<= 1) mx = fmaxf(mx, __shfl_xor(mx, off));
    float s = 0.f;
#pragma unroll
    for (int m = 0; m < 4; ++m) {
        int t = lane + 64 * m;
        v[m] = (t < LL) ? __expf(v[m] - mx) : 0.f;
        s += v[m];
    }
    for (int off = 1; off < 64; off <<= 1) s += __shfl_xor(s, off);
    float inv = 1.f / s;
#pragma unroll
    for (int m = 0; m < 4; ++m) {
        int t = lane + 64 * m;
        if (t < LL) attn[(size_t)b * LL + t] = v[m] * inv;
    }
}

// ---- K4: AUGRU scan, weights-stationary MFMA ----
// Wave w owns 16-col tile w (of 128) of each of {Wr, Wu, Wh}. Two MFMA phases
// per step (r/u/ax first, then (r*h)@Wh_h after the r gate).
__global__ __launch_bounds__(512, 2) void augru_v2(
    const unsigned short* __restrict__ h_bf, const float* __restrict__ attn,
    const int* __restrict__ hseq,
    const float* __restrict__ Wr, const float* __restrict__ Wu,
    const float* __restrict__ Wht,
    const float* __restrict__ br, const float* __restrict__ bu,
    const float* __restrict__ bh, float* __restrict__ evolved) {
    __shared__ alignas(16) unsigned short xf[2048];
    __shared__ alignas(16) unsigned short hf[2048];
    __shared__ alignas(16) unsigned short rhf[2048];
    __shared__ float rb_[8 * 132], ub_[8 * 132], axb[8 * 132], ahb[8 * 132];
    __shared__ float hs[8 * 132];
    const int tid = threadIdx.x;
    const int w = tid >> 6;
    const int lane = tid & 63;
    const int b0 = blockIdx.x * GR;
    const int grow = tid >> 6;
    const int dd = tid & 63;
    const float br0 = br[dd], br1 = br[dd + 64];
    const float bu0 = bu[dd], bu1 = bu[dd + 64];
    const float bh0 = bh[dd], bh1 = bh[dd + 64];
    // weight frags: cols w*16+(l&15); Wr/Wu k=0..255 (x then h), Wh split x/h
    s16x8 wr[8], wu[8], wx[4], whh[4];
    {
        int r = w * 16 + (lane & 15);
        int kg = (lane >> 4) * 8;
#pragma unroll
        for (int kc = 0; kc < 8; ++kc) {
            wr[kc] = pack8g(Wr + (size_t)r * 256 + kc * 32 + kg);
            wu[kc] = pack8g(Wu + (size_t)r * 256 + kc * 32 + kg);
        }
#pragma unroll
        for (int kc = 0; kc < 4; ++kc) {
            wx[kc] = pack8g(Wht + (size_t)r * 256 + kc * 32 + kg);
            whh[kc] = pack8g(Wht + (size_t)r * 256 + 128 + kc * 32 + kg);
        }
    }
    for (int i = tid; i < 2048; i += 512) { xf[i] = 0; hf[i] = 0; rhf[i] = 0; }
    for (int i = tid; i < 8 * 132; i += 512) hs[i] = 0.f;
    __syncthreads();
    const int pkc = (tid & 255) >> 6;
    const int plane = tid & 63;
    const int prow = plane & 15;
    const int pko = pkc * 32 + ((plane >> 4) & 3) * 8;
    for (int tt = 0; tt < LL; ++tt) {
        // ---- P1: pack x (bf16 direct copy) + h frags ----
        if (tid < 256) {
            if (prow < GR) {
                const unsigned short* src =
                    h_bf + ((size_t)(b0 + prow) * LL + tt) * 128 + pko;
                *(s16x8*)&xf[(pkc * 64 + plane) * 8] = *(const s16x8*)src;
            }
        } else {
            if (prow < GR)
                *(s16x8*)&hf[(pkc * 64 + plane) * 8] = pack8g(&hs[prow * 132 + pko]);
        }
        __syncthreads();
        // ---- P2: MFMA r/u/ax ----
        {
            f32x4 z = {0.f, 0.f, 0.f, 0.f};
            f32x4 ar = z, au = z, ax = z;
#pragma unroll
            for (int kc = 0; kc < 4; ++kc) {
                s16x8 xa = *(const s16x8*)&xf[(kc * 64 + lane) * 8];
                s16x8 ha = *(const s16x8*)&hf[(kc * 64 + lane) * 8];
                ar = MFMA(xa, wr[kc], ar); ar = MFMA(ha, wr[kc + 4], ar);
                au = MFMA(xa, wu[kc], au); au = MFMA(ha, wu[kc + 4], au);
                ax = MFMA(xa, wx[kc], ax);
            }
            if (lane < 32) {
                int rb = (lane >> 4) * 4;
                int cb = w * 16 + (lane & 15);
#pragma unroll
                for (int q = 0; q < 4; ++q) {
                    rb_[(rb + q) * 132 + cb] = ar[q];
                    ub_[(rb + q) * 132 + cb] = au[q];
                    axb[(rb + q) * 132 + cb] = ax[q];
                }
            }
        }
        __syncthreads();
        // ---- P3: r gate -> rh frags (bf16, frag-major scatter) ----
        {
            float rv0 = sigmf(rb_[grow * 132 + dd] + br0);
            float rv1 = sigmf(rb_[grow * 132 + dd + 64] + br1);
            float rh0 = rv0 * hs[grow * 132 + dd];
            float rh1 = rv1 * hs[grow * 132 + dd + 64];
            int d0 = dd, d1 = dd + 64;
            rhf[((d0 >> 5) * 64 + grow + 16 * ((d0 >> 3) & 3)) * 8 + (d0 & 7)] = f2bf(rh0);
            rhf[((d1 >> 5) * 64 + grow + 16 * ((d1 >> 3) & 3)) * 8 + (d1 & 7)] = f2bf(rh1);
        }
        __syncthreads();
        // ---- P4: MFMA (r*h) @ Wh_h ----
        {
            f32x4 ah4 = {0.f, 0.f, 0.f, 0.f};
#pragma unroll
            for (int kc = 0; kc < 4; ++kc) {
                s16x8 ra = *(const s16x8*)&rhf[(kc * 64 + lane) * 8];
                ah4 = MFMA(ra, whh[kc], ah4);
            }
            if (lane < 32) {
                int rb = (lane >> 4) * 4;
                int cb = w * 16 + (lane & 15);
#pragma unroll
                for (int q = 0; q < 4; ++q) ahb[(rb + q) * 132 + cb] = ah4[q];
            }
        }
        __syncthreads();
        // ---- P5: final gates + masked update ----
        {
            float at = attn[(size_t)(b0 + grow) * LL + tt];
            int mk = hseq[(size_t)(b0 + grow) * LL + tt];
            float u0 = sigmf(ub_[grow * 132 + dd] + bu0);
            float u1 = sigmf(ub_[grow * 132 + dd + 64] + bu1);
            float up0 = at * u0, up1 = at * u1;
            float ht0 = tanhf(axb[grow * 132 + dd] + ahb[grow * 132 + dd] + bh0);
            float ht1 = tanhf(axb[grow * 132 + dd + 64] + ahb[grow * 132 + dd + 64] + bh1);
            float ho0 = hs[grow * 132 + dd];
            float ho1 = hs[grow * 132 + dd + 64];
            float hn0 = (1.f - up0) * ho0 + up0 * ht0;
            float hn1 = (1.f - up1) * ho1 + up1 * ht1;
            hs[grow * 132 + dd] = (mk > 0) ? hn0 : ho0;
            hs[grow * 132 + dd + 64] = (mk > 0) ? hn1 : ho1;
        }
        __syncthreads();
    }
    evolved[(size_t)(b0 + grow) * 128 + dd] = hs[grow * 132 + dd];
    evolved[(size_t)(b0 + grow) * 128 + dd + 64] = hs[grow * 132 + dd + 64];
}

// ---- K5: feature concat + 3-layer MLP + sigmoid ----
__global__ __launch_bounds__(256) void mlp_kernel(
    const int* __restrict__ user_id, const int* __restrict__ item_id,
    const int* __restrict__ item_cat, const int* __restrict__ item_dur,
    const float* __restrict__ user_dense, const float* __restrict__ item_dense,
    const float* __restrict__ user_table, const float* __restrict__ item_table,
    const float* __restrict__ cat_table, const float* __restrict__ dur_table,
    const float* __restrict__ evolved,
    const float* __restrict__ W1t, const float* __restrict__ b1,
    const float* __restrict__ W2t, const float* __restrict__ b2,
    const float* __restrict__ W3, const float* __restrict__ b3,
    float* __restrict__ out) {
    __shared__ float Xs[MR][332];
    __shared__ float h1s[MR][256];
    __shared__ float h2s[MR][128];
    __shared__ int ids[4][MR];
    const int tid = threadIdx.x;
    const int b0 = blockIdx.x * MR;
    if (tid < MR) {
        ids[0][tid] = user_id[b0 + tid];
        ids[1][tid] = item_id[b0 + tid];
        ids[2][tid] = item_cat[b0 + tid];
        ids[3][tid] = item_dur[b0 + tid];
    }
    __syncthreads();
    for (int i = tid; i < MR * 332; i += 256) {
        int r = i / 332, c = i % 332;
        int b = b0 + r;
        float v;
        if (c < 64) v = user_table[(size_t)ids[0][r] * 64 + c];
        else if (c < 128) v = item_table[(size_t)ids[1][r] * 64 + (c - 64)];
        else if (c < 160) v = cat_table[(size_t)ids[2][r] * 32 + (c - 128)];
        else if (c < 176) v = dur_table[(size_t)ids[3][r] * 16 + (c - 160)];
        else if (c < 201) v = user_dense[(size_t)b * 25 + (c - 176)];
        else if (c < 204) v = item_dense[(size_t)b * 3 + (c - 201)];
        else v = evolved[(size_t)b * 128 + (c - 204)];
        Xs[r][c] = v;
    }
    __syncthreads();
    {
        float acc[MR] = {0, 0, 0, 0, 0, 0, 0, 0};
        for (int k = 0; k < 332; ++k) {
            float ww = W1t[(size_t)k * 256 + tid];
#pragma unroll
            for (int r = 0; r < MR; ++r) acc[r] += Xs[r][k] * ww;
        }
        float bb = b1[tid];
#pragma unroll
        for (int r = 0; r < MR; ++r) h1s[r][tid] = fmaxf(acc[r] + bb, 0.f);
    }
    __syncthreads();
    if (tid < 128) {
        float acc[MR] = {0, 0, 0, 0, 0, 0, 0, 0};
        for (int k = 0; k < 256; ++k) {
            float ww = W2t[(size_t)k * 128 + tid];
#pragma unroll
            for (int r = 0; r < MR; ++r) acc[r] += h1s[r][k] * ww;
        }
        float bb = b2[tid];
#pragma unroll
        for (int r = 0; r < MR; ++r) h2s[r][tid] = fmaxf(acc[r] + bb, 0.f);
    }
    __syncthreads();
    {
        int r = tid >> 5, j = tid & 31;
        float p = 0.f;
#pragma unroll
        for (int m = 0; m < 4; ++m) p += h2s[r][j + 32 * m] * W3[j + 32 * m];
        p += __shfl_xor(p, 16);
        p += __shfl_xor(p, 8);
        p += __shfl_xor(p, 4);
        p += __shfl_xor(p, 2);
        p += __shfl_xor(p, 1);
        if (j == 0) out[b0 + r] = 1.f / (1.f + __expf(-(p + b3[0])));
    }
}

extern "C" void kernel_launch(void* const* d_in, const int* in_sizes, int n_in,
                              void* d_out, int out_size, void* d_ws, size_t ws_size,
                              hipStream_t stream) {
    const int* user_id = (const int*)d_in[0];
    const int* item_id = (const int*)d_in[1];
    const int* item_cat = (const int*)d_in[2];
    const int* item_dur = (const int*)d_in[3];
    const int* hseq = (const int*)d_in[4];
    const float* user_dense = (const float*)d_in[5];
    const float* item_dense = (const float*)d_in[6];
    const float* user_table = (const float*)d_in[7];
    const float* item_table = (const float*)d_in[8];
    const float* cat_table = (const float*)d_in[9];
    const float* dur_table = (const float*)d_in[10];
    const float* hist_table = (const float*)d_in[11];
    const float* projW = (const float*)d_in[12];
    const float* gWi = (const float*)d_in[13];
    const float* gWh = (const float*)d_in[14];
    const float* gbi = (const float*)d_in[15];
    const float* gbh = (const float*)d_in[16];
    const float* aWr = (const float*)d_in[17];
    const float* abr = (const float*)d_in[18];
    const float* aWu = (const float*)d_in[19];
    const float* abu = (const float*)d_in[20];
    const float* aWh = (const float*)d_in[21];
    const float* abh = (const float*)d_in[22];
    const float* mW1 = (const float*)d_in[23];
    const float* mb1 = (const float*)d_in[24];
    const float* mW2 = (const float*)d_in[25];
    const float* mb2 = (const float*)d_in[26];
    const float* mW3 = (const float*)d_in[27];
    const float* mb3 = (const float*)d_in[28];
    float* out = (float*)d_out;

    // workspace layout (float slots); total ~110.7 MB
    float* ws = (float*)d_ws;
    float* target = ws;                                   // 262144 f
    unsigned short* h_bf = (unsigned short*)(ws + 262144);// 2048*200*128 bf16 = 26214400 f-slots
    float* scores = ws + 262144 + 26214400;               // 409600 f
    float* attn = scores + 409600;                        // 409600 f
    float* evolved = attn + 409600;                       // 262144 f
    float* W1t = evolved + 262144;                        // 84992 f
    float* W2t = W1t + 84992;                             // 32768 f

    hipLaunchKernelGGL(transpose_kernel, dim3(332), dim3(256), 0, stream, mW1, W1t, 256, 332);
    hipLaunchKernelGGL(transpose_kernel, dim3(256), dim3(128), 0, stream, mW2, W2t, 128, 256);
    hipLaunchKernelGGL(target_kernel, dim3(2048), dim3(128), 0, stream,
                       item_id, item_table, projW, target);
    hipLaunchKernelGGL(gru_v2, dim3(BB / GR), dim3(512), 0, stream,
                       hseq, hist_table, gWi, gWh, gbi, gbh, target, h_bf, scores);
    hipLaunchKernelGGL(softmax_kernel, dim3(BB / 4), dim3(256), 0, stream, scores, hseq, attn);
    hipLaunchKernelGGL(augru_v2, dim3(BB / GR), dim3(512), 0, stream,
                       h_bf, attn, hseq, aWr, aWu, aWh, abr, abu, abh, evolved);
    hipLaunchKernelGGL(mlp_kernel, dim3(BB / MR), dim3(256), 0, stream,
                       user_id, item_id, item_cat, item_dur, user_dense, item_dense,
                       user_table, item_table, cat_table, dur_table, evolved,
                       W1t, mb1, W2t, mb2, mW3, mb3, out);
}

// Round 3
// 758.682 us; speedup vs baseline: 13.5763x; 1.0947x over previous
//
#include <hip/hip_runtime.h>
#include <cstdint>
#include <cstddef>

// ---- problem constants ----
#define BB    2048
#define LL    200
#define GR    8      // batch rows per block in scan kernels
#define MR    8      // batch rows per block in MLP

typedef __attribute__((ext_vector_type(4))) float f32x4;
typedef __attribute__((ext_vector_type(8))) short s16x8;

__device__ __forceinline__ float sigmf(float x) { return 1.f / (1.f + __expf(-x)); }
__device__ __forceinline__ float tanhfast(float x) {
    float xc = fminf(15.f, fmaxf(-15.f, x));
    float e = __expf(2.f * xc);
    return (e - 1.f) / (e + 1.f);
}
__device__ __forceinline__ float dot4(float4 a, float4 b) {
    return a.x * b.x + a.y * b.y + a.z * b.z + a.w * b.w;
}
__device__ __forceinline__ float4 ld4(const float* p) { return *(const float4*)p; }
__device__ __forceinline__ void st4(float* p, float4 v) { *(float4*)p = v; }

__device__ __forceinline__ unsigned short f2bf(float f) {  // RNE
    union { float f; unsigned u; } v; v.f = f;
    unsigned r = (v.u + 0x7FFFu + ((v.u >> 16) & 1u)) >> 16;
    return (unsigned short)r;
}
__device__ __forceinline__ s16x8 pack8g(const float* p) {
    float4 a = ld4(p), b = ld4(p + 4);
    s16x8 o;
    o[0] = (short)f2bf(a.x); o[1] = (short)f2bf(a.y);
    o[2] = (short)f2bf(a.z); o[3] = (short)f2bf(a.w);
    o[4] = (short)f2bf(b.x); o[5] = (short)f2bf(b.y);
    o[6] = (short)f2bf(b.z); o[7] = (short)f2bf(b.w);
    return o;
}
__device__ __forceinline__ s16x8 cvt8(float4 a, float4 b) {
    s16x8 o;
    o[0] = (short)f2bf(a.x); o[1] = (short)f2bf(a.y);
    o[2] = (short)f2bf(a.z); o[3] = (short)f2bf(a.w);
    o[4] = (short)f2bf(b.x); o[5] = (short)f2bf(b.y);
    o[6] = (short)f2bf(b.z); o[7] = (short)f2bf(b.w);
    return o;
}
#define MFMA(a, b, c) __builtin_amdgcn_mfma_f32_16x16x32_bf16((a), (b), (c), 0, 0, 0)

// Raw barrier: LDS-drain only; global prefetch loads stay in flight.
#define BAR() do { \
    asm volatile("s_waitcnt lgkmcnt(0)" ::: "memory"); \
    __builtin_amdgcn_sched_barrier(0); \
    __builtin_amdgcn_s_barrier(); \
    __builtin_amdgcn_sched_barrier(0); \
} while (0)

// ---- K0: transpose small weight matrices ----
__global__ void transpose_kernel(const float* __restrict__ src, float* __restrict__ dst,
                                 int rows, int cols) {
    int k = blockIdx.x;
    for (int j = threadIdx.x; j < rows; j += blockDim.x)
        dst[(size_t)k * rows + j] = src[(size_t)j * cols + k];
}

// ---- K1: target = item_table[item_id] @ proj_W^T ----
__global__ __launch_bounds__(128) void target_kernel(
    const int* __restrict__ item_id, const float* __restrict__ item_table,
    const float* __restrict__ projW, float* __restrict__ target) {
    __shared__ float ie[64];
    int b = blockIdx.x, d = threadIdx.x;
    if (d < 64) ie[d] = item_table[(size_t)item_id[b] * 64 + d];
    __syncthreads();
    float acc = 0.f;
    const float* w = projW + (size_t)d * 64;
#pragma unroll
    for (int k = 0; k < 64; k += 4) acc += dot4(ld4(&ie[k]), ld4(w + k));
    target[(size_t)b * 128 + d] = acc;
}

// ---- K2: GRU scan v3 — single phase/step, in-register gates, raw barriers ----
// Wave w owns dims [16w,16w+16) of all three gates (Wi/Wh rows {16w,128+16w,256+16w}).
// h state lives in per-lane registers. xf/hf/scoreb double-buffered by parity.
__global__ __launch_bounds__(512, 2) void gru_v3(
    const int* __restrict__ hseq, const float* __restrict__ hist,
    const float* __restrict__ Wi, const float* __restrict__ Wh,
    const float* __restrict__ bi, const float* __restrict__ bh,
    const float* __restrict__ target,
    unsigned short* __restrict__ h_bf, float* __restrict__ scores) {
    __shared__ alignas(16) unsigned short xf[2][2048];
    __shared__ alignas(16) unsigned short hf[2][2048];
    __shared__ float scoreb[2][64];   // [parity][row*8 + wave]
    __shared__ int sq[GR * LL];
    const int tid = threadIdx.x;
    const int w = tid >> 6, lane = tid & 63;
    const int b0 = blockIdx.x * GR;
    const int cb = (w << 4) | (lane & 15);   // owned gate-dim (0..127)
    const int rb = (lane >> 4) * 4;          // row base (valid when lane<32)
    const int kc_ = cb >> 5, kq_ = (cb >> 3) & 3, jj = cb & 7;  // hf scatter coords
    // persistent weight fragments (96 VGPR)
    s16x8 wir[4], wiz[4], win[4], whr[4], whz[4], whn[4];
    {
        int c = lane & 15, kg = (lane >> 4) * 8;
#pragma unroll
        for (int kc = 0; kc < 4; ++kc) {
            int ko = kc * 32 + kg;
            wir[kc] = pack8g(Wi + (size_t)(w * 16 + c) * 128 + ko);
            wiz[kc] = pack8g(Wi + (size_t)(128 + w * 16 + c) * 128 + ko);
            win[kc] = pack8g(Wi + (size_t)(256 + w * 16 + c) * 128 + ko);
            whr[kc] = pack8g(Wh + (size_t)(w * 16 + c) * 128 + ko);
            whz[kc] = pack8g(Wh + (size_t)(128 + w * 16 + c) * 128 + ko);
            whn[kc] = pack8g(Wh + (size_t)(256 + w * 16 + c) * 128 + ko);
        }
    }
    const float bi_r = bi[cb], bi_z = bi[128 + cb], bi_n = bi[256 + cb];
    const float bh_r = bh[cb], bh_z = bh[128 + cb], bh_n = bh[256 + cb];
    float tgq[4] = {0, 0, 0, 0};
    float hold[4] = {0, 0, 0, 0};
    if (lane < 32) {
#pragma unroll
        for (int q = 0; q < 4; ++q) tgq[q] = target[(size_t)(b0 + rb + q) * 128 + cb];
    }
    for (int i = tid; i < 2048; i += 512) {
        xf[0][i] = 0; xf[1][i] = 0; hf[0][i] = 0; hf[1][i] = 0;
    }
    if (tid < 128) ((float*)scoreb)[tid] = 0.f;
    for (int i = tid; i < GR * LL; i += 512)
        sq[i] = hseq[(size_t)(b0 + i / LL) * LL + i % LL];
    __syncthreads();
    float4 pA0, pA1, pB0, pB1;
    if (lane < 16) {   // x(0) direct + issue x(1)
        int idx0 = sq[w * LL + 0];
        const float* p = hist + (size_t)idx0 * 128 + lane * 8;
        *(s16x8*)&xf[0][(((lane >> 2) * 64) + (lane & 3) * 16 + w) * 8] =
            cvt8(ld4(p), ld4(p + 4));
        int idx1 = sq[w * LL + 1];
        const float* p1 = hist + (size_t)idx1 * 128 + lane * 8;
        pA0 = ld4(p1); pA1 = ld4(p1 + 4);
    }
    __syncthreads();

#define GSTEP(TT, RD, C0, C1, N0, N1) { \
    const int tt = (TT); \
    if (lane < 16) { \
        *(s16x8*)&xf[RD ^ 1][(((lane >> 2) * 64) + (lane & 3) * 16 + w) * 8] = cvt8(C0, C1); \
        int nidx = sq[w * LL + (tt + 2 < LL ? tt + 2 : LL - 1)]; \
        const float* pp = hist + (size_t)nidx * 128 + lane * 8; \
        N0 = ld4(pp); N1 = ld4(pp + 4); \
    } \
    if (tt > 0 && lane == 16) { \
        float s = 0.f; \
        _Pragma("unroll") for (int wv = 0; wv < 8; ++wv) s += scoreb[RD ^ 1][w * 8 + wv]; \
        scores[(size_t)(b0 + w) * LL + tt - 1] = s * 0.08838834764831845f; \
    } \
    f32x4 ir = {0,0,0,0}, iz = {0,0,0,0}, in_ = {0,0,0,0}; \
    f32x4 hr = {0,0,0,0}, hz = {0,0,0,0}, hn_ = {0,0,0,0}; \
    _Pragma("unroll") for (int kc = 0; kc < 4; ++kc) { \
        s16x8 xa = *(const s16x8*)&xf[RD][(kc * 64 + lane) * 8]; \
        s16x8 ha = *(const s16x8*)&hf[RD][(kc * 64 + lane) * 8]; \
        ir = MFMA(xa, wir[kc], ir);  hr = MFMA(ha, whr[kc], hr); \
        iz = MFMA(xa, wiz[kc], iz);  hz = MFMA(ha, whz[kc], hz); \
        in_ = MFMA(xa, win[kc], in_); hn_ = MFMA(ha, whn[kc], hn_); \
    } \
    if (lane < 32) { \
        float p[4]; \
        _Pragma("unroll") for (int q = 0; q < 4; ++q) { \
            float r = sigmf(ir[q] + bi_r + hr[q] + bh_r); \
            float z = sigmf(iz[q] + bi_z + hz[q] + bh_z); \
            float n = tanhfast(in_[q] + bi_n + r * (hn_[q] + bh_n)); \
            float hv = (1.f - z) * n + z * hold[q]; \
            hold[q] = hv; \
            unsigned short hb = f2bf(hv); \
            h_bf[((size_t)(b0 + rb + q) * LL + tt) * 128 + cb] = hb; \
            hf[RD ^ 1][(kc_ * 64 + kq_ * 16 + (rb + q)) * 8 + jj] = (short)hb; \
            p[q] = hv * tgq[q]; \
        } \
        _Pragma("unroll") for (int off = 1; off < 16; off <<= 1) { \
            _Pragma("unroll") for (int q = 0; q < 4; ++q) p[q] += __shfl_xor(p[q], off); \
        } \
        if ((lane & 15) == 0) { \
            _Pragma("unroll") for (int q = 0; q < 4; ++q) scoreb[RD][(rb + q) * 8 + w] = p[q]; \
        } \
    } \
    BAR(); \
}

    for (int t2 = 0; t2 < LL / 2; ++t2) {
        GSTEP(2 * t2,     0, pA0, pA1, pB0, pB1);
        GSTEP(2 * t2 + 1, 1, pB0, pB1, pA0, pA1);
    }
#undef GSTEP
    if (lane == 16) {   // final score (tt=199, parity 1)
        float s = 0.f;
#pragma unroll
        for (int wv = 0; wv < 8; ++wv) s += scoreb[1][w * 8 + wv];
        scores[(size_t)(b0 + w) * LL + LL - 1] = s * 0.08838834764831845f;
    }
}

// ---- K3: masked softmax over L=200 per batch row ----
__global__ __launch_bounds__(256) void softmax_kernel(
    const float* __restrict__ scores, const int* __restrict__ hseq,
    float* __restrict__ attn) {
    int w = threadIdx.x >> 6;
    int lane = threadIdx.x & 63;
    int b = blockIdx.x * 4 + w;
    float v[4];
#pragma unroll
    for (int m = 0; m < 4; ++m) {
        int t = lane + 64 * m;
        if (t < LL) {
            float s = scores[(size_t)b * LL + t];
            v[m] = (hseq[(size_t)b * LL + t] > 0) ? s : -1e9f;
        } else
            v[m] = -3.0e38f;
    }
    float mx = fmaxf(fmaxf(v[0], v[1]), fmaxf(v[2], v[3]));
    for (int off = 1; off < 64; off <<= 1) mx = fmaxf(mx, __shfl_xor(mx, off));
    float s = 0.f;
#pragma unroll
    for (int m = 0; m < 4; ++m) {
        int t = lane + 64 * m;
        v[m] = (t < LL) ? __expf(v[m] - mx) : 0.f;
        s += v[m];
    }
    for (int off = 1; off < 64; off <<= 1) s += __shfl_xor(s, off);
    float inv = 1.f / s;
#pragma unroll
    for (int m = 0; m < 4; ++m) {
        int t = lane + 64 * m;
        if (t < LL) attn[(size_t)b * LL + t] = v[m] * inv;
    }
}

// ---- K4: AUGRU scan v3 — 2 phases/step, in-register h, raw barriers ----
__global__ __launch_bounds__(512, 2) void augru_v3(
    const unsigned short* __restrict__ h_bf, const float* __restrict__ attn,
    const int* __restrict__ hseq,
    const float* __restrict__ Wr, const float* __restrict__ Wu,
    const float* __restrict__ Wht,
    const float* __restrict__ br, const float* __restrict__ bu,
    const float* __restrict__ bh, float* __restrict__ evolved) {
    __shared__ alignas(16) unsigned short xf[2][2048];
    __shared__ alignas(16) unsigned short hf[2][2048];
    __shared__ alignas(16) unsigned short rhf[2048];
    __shared__ float attl[GR * LL];
    __shared__ float mskl[GR * LL];
    const int tid = threadIdx.x;
    const int w = tid >> 6, lane = tid & 63;
    const int b0 = blockIdx.x * GR;
    const int cb = (w << 4) | (lane & 15);
    const int rb = (lane >> 4) * 4;
    const int kc_ = cb >> 5, kq_ = (cb >> 3) & 3, jj = cb & 7;
    s16x8 wr_[8], wu_[8], wx_[4], wh_[4];
    {
        int c = lane & 15, kg = (lane >> 4) * 8;
        int r0 = w * 16 + c;
#pragma unroll
        for (int kc = 0; kc < 8; ++kc) {
            wr_[kc] = pack8g(Wr + (size_t)r0 * 256 + kc * 32 + kg);
            wu_[kc] = pack8g(Wu + (size_t)r0 * 256 + kc * 32 + kg);
        }
#pragma unroll
        for (int kc = 0; kc < 4; ++kc) {
            wx_[kc] = pack8g(Wht + (size_t)r0 * 256 + kc * 32 + kg);
            wh_[kc] = pack8g(Wht + (size_t)r0 * 256 + 128 + kc * 32 + kg);
        }
    }
    const float br_c = br[cb], bu_c = bu[cb], bh_c = bh[cb];
    float hold[4] = {0, 0, 0, 0};
    for (int i = tid; i < 2048; i += 512) {
        xf[0][i] = 0; xf[1][i] = 0; hf[0][i] = 0; hf[1][i] = 0; rhf[i] = 0;
    }
    for (int i = tid; i < GR * LL; i += 512) {
        int r = i / LL, t = i % LL;
        attl[i] = attn[(size_t)(b0 + r) * LL + t];
        mskl[i] = (hseq[(size_t)(b0 + r) * LL + t] > 0) ? 1.f : 0.f;
    }
    __syncthreads();
    s16x8 pA, pB;
    if (lane < 16) {
        xf[0][0] = xf[0][0];  // no-op
        *(s16x8*)&xf[0][(((lane >> 2) * 64) + (lane & 3) * 16 + w) * 8] =
            *(const s16x8*)(h_bf + ((size_t)(b0 + w) * LL + 0) * 128 + lane * 8);
        pA = *(const s16x8*)(h_bf + ((size_t)(b0 + w) * LL + 1) * 128 + lane * 8);
    }
    __syncthreads();

#define ASTEP(TT, RD, CUR, NXT) { \
    const int tt = (TT); \
    if (lane < 16) { \
        *(s16x8*)&xf[RD ^ 1][(((lane >> 2) * 64) + (lane & 3) * 16 + w) * 8] = CUR; \
        int nt = tt + 2 < LL ? tt + 2 : LL - 1; \
        NXT = *(const s16x8*)(h_bf + ((size_t)(b0 + w) * LL + nt) * 128 + lane * 8); \
    } \
    f32x4 ar = {0,0,0,0}, au = {0,0,0,0}, ax = {0,0,0,0}; \
    _Pragma("unroll") for (int kc = 0; kc < 4; ++kc) { \
        s16x8 xa = *(const s16x8*)&xf[RD][(kc * 64 + lane) * 8]; \
        s16x8 ha = *(const s16x8*)&hf[RD][(kc * 64 + lane) * 8]; \
        ar = MFMA(xa, wr_[kc], ar); ar = MFMA(ha, wr_[kc + 4], ar); \
        au = MFMA(xa, wu_[kc], au); au = MFMA(ha, wu_[kc + 4], au); \
        ax = MFMA(xa, wx_[kc], ax); \
    } \
    if (lane < 32) { \
        _Pragma("unroll") for (int q = 0; q < 4; ++q) { \
            float r = sigmf(ar[q] + br_c); \
            rhf[(kc_ * 64 + kq_ * 16 + (rb + q)) * 8 + jj] = (short)f2bf(r * hold[q]); \
        } \
    } \
    BAR(); \
    f32x4 ah = {0,0,0,0}; \
    _Pragma("unroll") for (int kc = 0; kc < 4; ++kc) { \
        s16x8 ra = *(const s16x8*)&rhf[(kc * 64 + lane) * 8]; \
        ah = MFMA(ra, wh_[kc], ah); \
    } \
    if (lane < 32) { \
        _Pragma("unroll") for (int q = 0; q < 4; ++q) { \
            float u = sigmf(au[q] + bu_c); \
            float up = attl[(rb + q) * LL + tt] * u; \
            float ht = tanhfast(ax[q] + ah[q] + bh_c); \
            float hv = (1.f - up) * hold[q] + up * ht; \
            hold[q] = mskl[(rb + q) * LL + tt] > 0.5f ? hv : hold[q]; \
            hf[RD ^ 1][(kc_ * 64 + kq_ * 16 + (rb + q)) * 8 + jj] = (short)f2bf(hold[q]); \
        } \
    } \
    BAR(); \
}

    for (int t2 = 0; t2 < LL / 2; ++t2) {
        ASTEP(2 * t2,     0, pA, pB);
        ASTEP(2 * t2 + 1, 1, pB, pA);
    }
#undef ASTEP
    if (lane < 32) {
#pragma unroll
        for (int q = 0; q < 4; ++q)
            evolved[(size_t)(b0 + rb + q) * 128 + cb] = hold[q];
    }
}

// ---- K5: feature concat + 3-layer MLP + sigmoid ----
__global__ __launch_bounds__(256) void mlp_kernel(
    const int* __restrict__ user_id, const int* __restrict__ item_id,
    const int* __restrict__ item_cat, const int* __restrict__ item_dur,
    const float* __restrict__ user_dense, const float* __restrict__ item_dense,
    const float* __restrict__ user_table, const float* __restrict__ item_table,
    const float* __restrict__ cat_table, const float* __restrict__ dur_table,
    const float* __restrict__ evolved,
    const float* __restrict__ W1t, const float* __restrict__ b1,
    const float* __restrict__ W2t, const float* __restrict__ b2,
    const float* __restrict__ W3, const float* __restrict__ b3,
    float* __restrict__ out) {
    __shared__ float Xs[MR][332];
    __shared__ float h1s[MR][256];
    __shared__ float h2s[MR][128];
    __shared__ int ids[4][MR];
    const int tid = threadIdx.x;
    const int b0 = blockIdx.x * MR;
    if (tid < MR) {
        ids[0][tid] = user_id[b0 + tid];
        ids[1][tid] = item_id[b0 + tid];
        ids[2][tid] = item_cat[b0 + tid];
        ids[3][tid] = item_dur[b0 + tid];
    }
    __syncthreads();
    for (int i = tid; i < MR * 332; i += 256) {
        int r = i / 332, c = i % 332;
        int b = b0 + r;
        float v;
        if (c < 64) v = user_table[(size_t)ids[0][r] * 64 + c];
        else if (c < 128) v = item_table[(size_t)ids[1][r] * 64 + (c - 64)];
        else if (c < 160) v = cat_table[(size_t)ids[2][r] * 32 + (c - 128)];
        else if (c < 176) v = dur_table[(size_t)ids[3][r] * 16 + (c - 160)];
        else if (c < 201) v = user_dense[(size_t)b * 25 + (c - 176)];
        else if (c < 204) v = item_dense[(size_t)b * 3 + (c - 201)];
        else v = evolved[(size_t)b * 128 + (c - 204)];
        Xs[r][c] = v;
    }
    __syncthreads();
    {
        float acc[MR] = {0, 0, 0, 0, 0, 0, 0, 0};
        for (int k = 0; k < 332; ++k) {
            float ww = W1t[(size_t)k * 256 + tid];
#pragma unroll
            for (int r = 0; r < MR; ++r) acc[r] += Xs[r][k] * ww;
        }
        float bb = b1[tid];
#pragma unroll
        for (int r = 0; r < MR; ++r) h1s[r][tid] = fmaxf(acc[r] + bb, 0.f);
    }
    __syncthreads();
    if (tid < 128) {
        float acc[MR] = {0, 0, 0, 0, 0, 0, 0, 0};
        for (int k = 0; k < 256; ++k) {
            float ww = W2t[(size_t)k * 128 + tid];
#pragma unroll
            for (int r = 0; r < MR; ++r) acc[r] += h1s[r][k] * ww;
        }
        float bb = b2[tid];
#pragma unroll
        for (int r = 0; r < MR; ++r) h2s[r][tid] = fmaxf(acc[r] + bb, 0.f);
    }
    __syncthreads();
    {
        int r = tid >> 5, j = tid & 31;
        float p = 0.f;
#pragma unroll
        for (int m = 0; m < 4; ++m) p += h2s[r][j + 32 * m] * W3[j + 32 * m];
        p += __shfl_xor(p, 16);
        p += __shfl_xor(p, 8);
        p += __shfl_xor(p, 4);
        p += __shfl_xor(p, 2);
        p += __shfl_xor(p, 1);
        if (j == 0) out[b0 + r] = 1.f / (1.f + __expf(-(p + b3[0])));
    }
}

extern "C" void kernel_launch(void* const* d_in, const int* in_sizes, int n_in,
                              void* d_out, int out_size, void* d_ws, size_t ws_size,
                              hipStream_t stream) {
    const int* user_id = (const int*)d_in[0];
    const int* item_id = (const int*)d_in[1];
    const int* item_cat = (const int*)d_in[2];
    const int* item_dur = (const int*)d_in[3];
    const int* hseq = (const int*)d_in[4];
    const float* user_dense = (const float*)d_in[5];
    const float* item_dense = (const float*)d_in[6];
    const float* user_table = (const float*)d_in[7];
    const float* item_table = (const float*)d_in[8];
    const float* cat_table = (const float*)d_in[9];
    const float* dur_table = (const float*)d_in[10];
    const float* hist_table = (const float*)d_in[11];
    const float* projW = (const float*)d_in[12];
    const float* gWi = (const float*)d_in[13];
    const float* gWh = (const float*)d_in[14];
    const float* gbi = (const float*)d_in[15];
    const float* gbh = (const float*)d_in[16];
    const float* aWr = (const float*)d_in[17];
    const float* abr = (const float*)d_in[18];
    const float* aWu = (const float*)d_in[19];
    const float* abu = (const float*)d_in[20];
    const float* aWh = (const float*)d_in[21];
    const float* abh = (const float*)d_in[22];
    const float* mW1 = (const float*)d_in[23];
    const float* mb1 = (const float*)d_in[24];
    const float* mW2 = (const float*)d_in[25];
    const float* mb2 = (const float*)d_in[26];
    const float* mW3 = (const float*)d_in[27];
    const float* mb3 = (const float*)d_in[28];
    float* out = (float*)d_out;

    float* ws = (float*)d_ws;
    float* target = ws;                                    // 262144 f
    unsigned short* h_bf = (unsigned short*)(ws + 262144); // 26214400 f-slots
    float* scores = ws + 262144 + 26214400;                // 409600 f
    float* attn = scores + 409600;                         // 409600 f
    float* evolved = attn + 409600;                        // 262144 f
    float* W1t = evolved + 262144;                         // 84992 f
    float* W2t = W1t + 84992;                              // 32768 f

    hipLaunchKernelGGL(transpose_kernel, dim3(332), dim3(256), 0, stream, mW1, W1t, 256, 332);
    hipLaunchKernelGGL(transpose_kernel, dim3(256), dim3(128), 0, stream, mW2, W2t, 128, 256);
    hipLaunchKernelGGL(target_kernel, dim3(2048), dim3(128), 0, stream,
                       item_id, item_table, projW, target);
    hipLaunchKernelGGL(gru_v3, dim3(BB / GR), dim3(512), 0, stream,
                       hseq, hist_table, gWi, gWh, gbi, gbh, target, h_bf, scores);
    hipLaunchKernelGGL(softmax_kernel, dim3(BB / 4), dim3(256), 0, stream, scores, hseq, attn);
    hipLaunchKernelGGL(augru_v3, dim3(BB / GR), dim3(512), 0, stream,
                       h_bf, attn, hseq, aWr, aWu, aWh, abr, abu, abh, evolved);
    hipLaunchKernelGGL(mlp_kernel, dim3(BB / MR), dim3(256), 0, stream,
                       user_id, item_id, item_cat, item_dur, user_dense, item_dense,
                       user_table, item_table, cat_table, dur_table, evolved,
                       W1t, mb1, W2t, mb2, mW3, mb3, out);
}

// Round 4
// 473.333 us; speedup vs baseline: 21.7607x; 1.6029x over previous
//
#include <hip/hip_runtime.h>
#include <cstdint>
#include <cstddef>

// ---- problem constants ----
#define BB    2048
#define LL    200
#define GR    8      // batch rows per block in scan kernels
#define MR    8      // batch rows per block in MLP

typedef __attribute__((ext_vector_type(4))) float f32x4;
typedef __attribute__((ext_vector_type(8))) short s16x8;

__device__ __forceinline__ float fastrcp(float x) { return __builtin_amdgcn_rcpf(x); }
__device__ __forceinline__ float sigmf(float x) { return fastrcp(1.f + __expf(-x)); }
__device__ __forceinline__ float tanh2(float x) {
    return __builtin_fmaf(2.f, fastrcp(1.f + __expf(-2.f * x)), -1.f);
}
__device__ __forceinline__ float dot4(float4 a, float4 b) {
    return a.x * b.x + a.y * b.y + a.z * b.z + a.w * b.w;
}
__device__ __forceinline__ float4 ld4(const float* p) { return *(const float4*)p; }

__device__ __forceinline__ unsigned short f2bf(float f) {  // RNE
    union { float f; unsigned u; } v; v.f = f;
    unsigned r = (v.u + 0x7FFFu + ((v.u >> 16) & 1u)) >> 16;
    return (unsigned short)r;
}
__device__ __forceinline__ float bf2f(unsigned short b) {
    unsigned u = ((unsigned)b) << 16;
    union { unsigned u; float f; } v; v.u = u;
    return v.f;
}
__device__ __forceinline__ s16x8 pack8g(const float* p) {
    float4 a = ld4(p), b = ld4(p + 4);
    s16x8 o;
    o[0] = (short)f2bf(a.x); o[1] = (short)f2bf(a.y);
    o[2] = (short)f2bf(a.z); o[3] = (short)f2bf(a.w);
    o[4] = (short)f2bf(b.x); o[5] = (short)f2bf(b.y);
    o[6] = (short)f2bf(b.z); o[7] = (short)f2bf(b.w);
    return o;
}
#define MFMA(a, b, c) __builtin_amdgcn_mfma_f32_16x16x32_bf16((a), (b), (c), 0, 0, 0)

// Raw barrier: LDS-drain only; global prefetch loads stay in flight.
#define BAR() do { \
    asm volatile("s_waitcnt lgkmcnt(0)" ::: "memory"); \
    __builtin_amdgcn_sched_barrier(0); \
    __builtin_amdgcn_s_barrier(); \
    __builtin_amdgcn_sched_barrier(0); \
} while (0)

// redistribute f32x4 acc (rows rb..rb+3 in lanes 0-31) so every lane holds 2 rows
#define RED2(A, O0, O1) { \
    float s2_ = __shfl(A[2], srcl), s3_ = __shfl(A[3], srcl); \
    O0 = hi ? s2_ : A[0]; O1 = hi ? s3_ : A[1]; \
}

// ---- K-1: convert hist_table fp32 -> bf16 once ----
__global__ __launch_bounds__(256) void cvt_hist(const float* __restrict__ src,
                                                unsigned short* __restrict__ dst, int n8) {
    int i = blockIdx.x * 256 + threadIdx.x;
    if (i < n8) *(s16x8*)(dst + (size_t)i * 8) = pack8g(src + (size_t)i * 8);
}

// ---- K0: transpose small weight matrices ----
__global__ void transpose_kernel(const float* __restrict__ src, float* __restrict__ dst,
                                 int rows, int cols) {
    int k = blockIdx.x;
    for (int j = threadIdx.x; j < rows; j += blockDim.x)
        dst[(size_t)k * rows + j] = src[(size_t)j * cols + k];
}

// ---- K1: target = item_table[item_id] @ proj_W^T ----
__global__ __launch_bounds__(128) void target_kernel(
    const int* __restrict__ item_id, const float* __restrict__ item_table,
    const float* __restrict__ projW, float* __restrict__ target) {
    __shared__ float ie[64];
    int b = blockIdx.x, d = threadIdx.x;
    if (d < 64) ie[d] = item_table[(size_t)item_id[b] * 64 + d];
    __syncthreads();
    float acc = 0.f;
    const float* w = projW + (size_t)d * 64;
#pragma unroll
    for (int k = 0; k < 64; k += 4) acc += dot4(ld4(&ie[k]), ld4(w + k));
    target[(size_t)b * 128 + d] = acc;
}

// ---- K2: GRU scan v4 — fast gates on all 64 lanes, bf16 x, no score ----
__global__ __launch_bounds__(512, 2) void gru_v4(
    const int* __restrict__ hseq, const unsigned short* __restrict__ hist_bf,
    const float* __restrict__ Wi, const float* __restrict__ Wh,
    const float* __restrict__ bi, const float* __restrict__ bh,
    unsigned short* __restrict__ h_bf) {
    __shared__ alignas(16) unsigned short xf[2][2048];
    __shared__ alignas(16) unsigned short hf[2][2048];
    __shared__ int sq[GR * LL];
    const int tid = threadIdx.x;
    const int w = tid >> 6, lane = tid & 63;
    const int b0 = blockIdx.x * GR;
    const int cb = (w << 4) | (lane & 15);
    const int kc_ = cb >> 5, kq_ = (cb >> 3) & 3, jj = cb & 7;
    const int srcl = lane & 31;
    const bool hi = lane >= 32;
    const int rowb = ((lane & 31) >> 4) * 4 + (hi ? 2 : 0);   // this lane's 2 rows
    // persistent weight fragments (96 VGPR)
    s16x8 wir[4], wiz[4], win[4], whr[4], whz[4], whn[4];
    {
        int c = lane & 15, kg = (lane >> 4) * 8;
#pragma unroll
        for (int kc = 0; kc < 4; ++kc) {
            int ko = kc * 32 + kg;
            wir[kc] = pack8g(Wi + (size_t)(w * 16 + c) * 128 + ko);
            wiz[kc] = pack8g(Wi + (size_t)(128 + w * 16 + c) * 128 + ko);
            win[kc] = pack8g(Wi + (size_t)(256 + w * 16 + c) * 128 + ko);
            whr[kc] = pack8g(Wh + (size_t)(w * 16 + c) * 128 + ko);
            whz[kc] = pack8g(Wh + (size_t)(128 + w * 16 + c) * 128 + ko);
            whn[kc] = pack8g(Wh + (size_t)(256 + w * 16 + c) * 128 + ko);
        }
    }
    const float bi_r = bi[cb], bi_z = bi[128 + cb], bi_n = bi[256 + cb];
    const float bh_r = bh[cb], bh_z = bh[128 + cb], bh_n = bh[256 + cb];
    float hold0 = 0.f, hold1 = 0.f;
    for (int i = tid; i < 2048; i += 512) {
        xf[0][i] = 0; xf[1][i] = 0; hf[0][i] = 0; hf[1][i] = 0;
    }
    for (int i = tid; i < GR * LL; i += 512)
        sq[i] = hseq[(size_t)(b0 + i / LL) * LL + i % LL];
    __syncthreads();
    s16x8 pA, pB;
    if (lane < 16) {   // x(0) direct + fetch x(1)
        int idx0 = sq[w * LL + 0];
        *(s16x8*)&xf[0][(((lane >> 2) * 64) + (lane & 3) * 16 + w) * 8] =
            *(const s16x8*)(hist_bf + (size_t)idx0 * 128 + lane * 8);
        int idx1 = sq[w * LL + 1];
        pA = *(const s16x8*)(hist_bf + (size_t)idx1 * 128 + lane * 8);
    }
    __syncthreads();

#define GSTEP(TT, RD, CUR, NXT) { \
    const int tt = (TT); \
    if (lane < 16) { \
        *(s16x8*)&xf[RD ^ 1][(((lane >> 2) * 64) + (lane & 3) * 16 + w) * 8] = CUR; \
        int nidx = sq[w * LL + (tt + 2 < LL ? tt + 2 : LL - 1)]; \
        NXT = *(const s16x8*)(hist_bf + (size_t)nidx * 128 + lane * 8); \
    } \
    f32x4 ir = {0,0,0,0}, iz = {0,0,0,0}, in_ = {0,0,0,0}; \
    f32x4 hr = {0,0,0,0}, hz = {0,0,0,0}, hn_ = {0,0,0,0}; \
    _Pragma("unroll") for (int kc = 0; kc < 4; ++kc) { \
        s16x8 xa = *(const s16x8*)&xf[RD][(kc * 64 + lane) * 8]; \
        s16x8 ha = *(const s16x8*)&hf[RD][(kc * 64 + lane) * 8]; \
        ir = MFMA(xa, wir[kc], ir);  hr = MFMA(ha, whr[kc], hr); \
        iz = MFMA(xa, wiz[kc], iz);  hz = MFMA(ha, whz[kc], hz); \
        in_ = MFMA(xa, win[kc], in_); hn_ = MFMA(ha, whn[kc], hn_); \
    } \
    float xr0, xr1, xz0, xz1, xn0, xn1, yr0, yr1, yz0, yz1, yn0, yn1; \
    RED2(ir, xr0, xr1); RED2(iz, xz0, xz1); RED2(in_, xn0, xn1); \
    RED2(hr, yr0, yr1); RED2(hz, yz0, yz1); RED2(hn_, yn0, yn1); \
    { \
        float r = sigmf(xr0 + bi_r + yr0 + bh_r); \
        float z = sigmf(xz0 + bi_z + yz0 + bh_z); \
        float n = tanh2(xn0 + bi_n + r * (yn0 + bh_n)); \
        float hv = (1.f - z) * n + z * hold0; hold0 = hv; \
        unsigned short hb = f2bf(hv); \
        h_bf[((size_t)(b0 + rowb) * LL + tt) * 128 + cb] = hb; \
        hf[RD ^ 1][(kc_ * 64 + kq_ * 16 + rowb) * 8 + jj] = (short)hb; \
    } \
    { \
        float r = sigmf(xr1 + bi_r + yr1 + bh_r); \
        float z = sigmf(xz1 + bi_z + yz1 + bh_z); \
        float n = tanh2(xn1 + bi_n + r * (yn1 + bh_n)); \
        float hv = (1.f - z) * n + z * hold1; hold1 = hv; \
        unsigned short hb = f2bf(hv); \
        h_bf[((size_t)(b0 + rowb + 1) * LL + tt) * 128 + cb] = hb; \
        hf[RD ^ 1][(kc_ * 64 + kq_ * 16 + rowb + 1) * 8 + jj] = (short)hb; \
    } \
    BAR(); \
}

    for (int t2 = 0; t2 < LL / 2; ++t2) {
        GSTEP(2 * t2,     0, pA, pB);
        GSTEP(2 * t2 + 1, 1, pB, pA);
    }
#undef GSTEP
}

// ---- K3: fused scores + masked softmax (one block per batch row) ----
__global__ __launch_bounds__(256) void score_softmax(
    const unsigned short* __restrict__ h_bf, const float* __restrict__ target,
    const int* __restrict__ hseq, float* __restrict__ attn) {
    __shared__ float tg[128];
    __shared__ float rbuf[8];
    const int b = blockIdx.x, tid = threadIdx.x;
    const int wv = tid >> 6, lane = tid & 63;
    if (tid < 128) tg[tid] = target[(size_t)b * 128 + tid];
    __syncthreads();
    float v = -3.0e38f;
    if (tid < LL) {
        const unsigned short* hp = h_bf + ((size_t)b * LL + tid) * 128;
        float acc = 0.f;
#pragma unroll
        for (int k = 0; k < 128; k += 8) {
            s16x8 hv = *(const s16x8*)(hp + k);
#pragma unroll
            for (int j = 0; j < 8; ++j)
                acc = __builtin_fmaf(bf2f((unsigned short)hv[j]), tg[k + j], acc);
        }
        v = (hseq[(size_t)b * LL + tid] > 0) ? acc * 0.08838834764831845f : -1e9f;
    }
    float mx = v;
    for (int off = 1; off < 64; off <<= 1) mx = fmaxf(mx, __shfl_xor(mx, off));
    if (lane == 0) rbuf[wv] = mx;
    __syncthreads();
    mx = fmaxf(fmaxf(rbuf[0], rbuf[1]), fmaxf(rbuf[2], rbuf[3]));
    float e = (tid < LL) ? __expf(v - mx) : 0.f;
    float s = e;
    for (int off = 1; off < 64; off <<= 1) s += __shfl_xor(s, off);
    if (lane == 0) rbuf[4 + wv] = s;
    __syncthreads();
    s = rbuf[4] + rbuf[5] + rbuf[6] + rbuf[7];
    if (tid < LL) attn[(size_t)b * LL + tid] = e / s;
}

// ---- K4: AUGRU scan v4 ----
__global__ __launch_bounds__(512, 2) void augru_v4(
    const unsigned short* __restrict__ h_bf, const float* __restrict__ attn,
    const int* __restrict__ hseq,
    const float* __restrict__ Wr, const float* __restrict__ Wu,
    const float* __restrict__ Wht,
    const float* __restrict__ br, const float* __restrict__ bu,
    const float* __restrict__ bh, float* __restrict__ evolved) {
    __shared__ alignas(16) unsigned short xf[2][2048];
    __shared__ alignas(16) unsigned short hf[2][2048];
    __shared__ alignas(16) unsigned short rhf[2048];
    __shared__ float attl[GR * LL];
    __shared__ float mskl[GR * LL];
    const int tid = threadIdx.x;
    const int w = tid >> 6, lane = tid & 63;
    const int b0 = blockIdx.x * GR;
    const int cb = (w << 4) | (lane & 15);
    const int kc_ = cb >> 5, kq_ = (cb >> 3) & 3, jj = cb & 7;
    const int srcl = lane & 31;
    const bool hi = lane >= 32;
    const int rowb = ((lane & 31) >> 4) * 4 + (hi ? 2 : 0);
    s16x8 wr_[8], wu_[8], wx_[4], wh_[4];
    {
        int c = lane & 15, kg = (lane >> 4) * 8;
        int r0 = w * 16 + c;
#pragma unroll
        for (int kc = 0; kc < 8; ++kc) {
            wr_[kc] = pack8g(Wr + (size_t)r0 * 256 + kc * 32 + kg);
            wu_[kc] = pack8g(Wu + (size_t)r0 * 256 + kc * 32 + kg);
        }
#pragma unroll
        for (int kc = 0; kc < 4; ++kc) {
            wx_[kc] = pack8g(Wht + (size_t)r0 * 256 + kc * 32 + kg);
            wh_[kc] = pack8g(Wht + (size_t)r0 * 256 + 128 + kc * 32 + kg);
        }
    }
    const float br_c = br[cb], bu_c = bu[cb], bh_c = bh[cb];
    float hold0 = 0.f, hold1 = 0.f;
    for (int i = tid; i < 2048; i += 512) {
        xf[0][i] = 0; xf[1][i] = 0; hf[0][i] = 0; hf[1][i] = 0; rhf[i] = 0;
    }
    for (int i = tid; i < GR * LL; i += 512) {
        int r = i / LL, t = i % LL;
        attl[i] = attn[(size_t)(b0 + r) * LL + t];
        mskl[i] = (hseq[(size_t)(b0 + r) * LL + t] > 0) ? 1.f : 0.f;
    }
    __syncthreads();
    s16x8 pA, pB;
    if (lane < 16) {
        *(s16x8*)&xf[0][(((lane >> 2) * 64) + (lane & 3) * 16 + w) * 8] =
            *(const s16x8*)(h_bf + ((size_t)(b0 + w) * LL + 0) * 128 + lane * 8);
        pA = *(const s16x8*)(h_bf + ((size_t)(b0 + w) * LL + 1) * 128 + lane * 8);
    }
    __syncthreads();

#define ASTEP(TT, RD, CUR, NXT) { \
    const int tt = (TT); \
    if (lane < 16) { \
        *(s16x8*)&xf[RD ^ 1][(((lane >> 2) * 64) + (lane & 3) * 16 + w) * 8] = CUR; \
        int nt = tt + 2 < LL ? tt + 2 : LL - 1; \
        NXT = *(const s16x8*)(h_bf + ((size_t)(b0 + w) * LL + nt) * 128 + lane * 8); \
    } \
    f32x4 ar = {0,0,0,0}, au = {0,0,0,0}, ax = {0,0,0,0}; \
    _Pragma("unroll") for (int kc = 0; kc < 4; ++kc) { \
        s16x8 xa = *(const s16x8*)&xf[RD][(kc * 64 + lane) * 8]; \
        s16x8 ha = *(const s16x8*)&hf[RD][(kc * 64 + lane) * 8]; \
        ar = MFMA(xa, wr_[kc], ar); ar = MFMA(ha, wr_[kc + 4], ar); \
        au = MFMA(xa, wu_[kc], au); au = MFMA(ha, wu_[kc + 4], au); \
        ax = MFMA(xa, wx_[kc], ax); \
    } \
    { \
        float a0, a1; \
        RED2(ar, a0, a1); \
        float r0 = sigmf(a0 + br_c), r1 = sigmf(a1 + br_c); \
        rhf[(kc_ * 64 + kq_ * 16 + rowb) * 8 + jj] = (short)f2bf(r0 * hold0); \
        rhf[(kc_ * 64 + kq_ * 16 + rowb + 1) * 8 + jj] = (short)f2bf(r1 * hold1); \
    } \
    BAR(); \
    f32x4 ah = {0,0,0,0}; \
    _Pragma("unroll") for (int kc = 0; kc < 4; ++kc) { \
        s16x8 ra = *(const s16x8*)&rhf[(kc * 64 + lane) * 8]; \
        ah = MFMA(ra, wh_[kc], ah); \
    } \
    { \
        float u0, u1, x0, x1, g0, g1; \
        RED2(au, u0, u1); RED2(ax, x0, x1); RED2(ah, g0, g1); \
        float uu0 = sigmf(u0 + bu_c), uu1 = sigmf(u1 + bu_c); \
        float up0 = attl[rowb * LL + tt] * uu0; \
        float up1 = attl[(rowb + 1) * LL + tt] * uu1; \
        float ht0 = tanh2(x0 + g0 + bh_c), ht1 = tanh2(x1 + g1 + bh_c); \
        float hv0 = (1.f - up0) * hold0 + up0 * ht0; \
        float hv1 = (1.f - up1) * hold1 + up1 * ht1; \
        hold0 = mskl[rowb * LL + tt] > 0.5f ? hv0 : hold0; \
        hold1 = mskl[(rowb + 1) * LL + tt] > 0.5f ? hv1 : hold1; \
        hf[RD ^ 1][(kc_ * 64 + kq_ * 16 + rowb) * 8 + jj] = (short)f2bf(hold0); \
        hf[RD ^ 1][(kc_ * 64 + kq_ * 16 + rowb + 1) * 8 + jj] = (short)f2bf(hold1); \
    } \
    BAR(); \
}

    for (int t2 = 0; t2 < LL / 2; ++t2) {
        ASTEP(2 * t2,     0, pA, pB);
        ASTEP(2 * t2 + 1, 1, pB, pA);
    }
#undef ASTEP
    evolved[(size_t)(b0 + rowb) * 128 + cb] = hold0;
    evolved[(size_t)(b0 + rowb + 1) * 128 + cb] = hold1;
}

// ---- K5: feature concat + 3-layer MLP + sigmoid ----
__global__ __launch_bounds__(256) void mlp_kernel(
    const int* __restrict__ user_id, const int* __restrict__ item_id,
    const int* __restrict__ item_cat, const int* __restrict__ item_dur,
    const float* __restrict__ user_dense, const float* __restrict__ item_dense,
    const float* __restrict__ user_table, const float* __restrict__ item_table,
    const float* __restrict__ cat_table, const float* __restrict__ dur_table,
    const float* __restrict__ evolved,
    const float* __restrict__ W1t, const float* __restrict__ b1,
    const float* __restrict__ W2t, const float* __restrict__ b2,
    const float* __restrict__ W3, const float* __restrict__ b3,
    float* __restrict__ out) {
    __shared__ float Xs[MR][332];
    __shared__ float h1s[MR][256];
    __shared__ float h2s[MR][128];
    __shared__ int ids[4][MR];
    const int tid = threadIdx.x;
    const int b0 = blockIdx.x * MR;
    if (tid < MR) {
        ids[0][tid] = user_id[b0 + tid];
        ids[1][tid] = item_id[b0 + tid];
        ids[2][tid] = item_cat[b0 + tid];
        ids[3][tid] = item_dur[b0 + tid];
    }
    __syncthreads();
    for (int i = tid; i < MR * 332; i += 256) {
        int r = i / 332, c = i % 332;
        int b = b0 + r;
        float v;
        if (c < 64) v = user_table[(size_t)ids[0][r] * 64 + c];
        else if (c < 128) v = item_table[(size_t)ids[1][r] * 64 + (c - 64)];
        else if (c < 160) v = cat_table[(size_t)ids[2][r] * 32 + (c - 128)];
        else if (c < 176) v = dur_table[(size_t)ids[3][r] * 16 + (c - 160)];
        else if (c < 201) v = user_dense[(size_t)b * 25 + (c - 176)];
        else if (c < 204) v = item_dense[(size_t)b * 3 + (c - 201)];
        else v = evolved[(size_t)b * 128 + (c - 204)];
        Xs[r][c] = v;
    }
    __syncthreads();
    {
        float acc[MR] = {0, 0, 0, 0, 0, 0, 0, 0};
        for (int k = 0; k < 332; ++k) {
            float ww = W1t[(size_t)k * 256 + tid];
#pragma unroll
            for (int r = 0; r < MR; ++r) acc[r] += Xs[r][k] * ww;
        }
        float bb = b1[tid];
#pragma unroll
        for (int r = 0; r < MR; ++r) h1s[r][tid] = fmaxf(acc[r] + bb, 0.f);
    }
    __syncthreads();
    if (tid < 128) {
        float acc[MR] = {0, 0, 0, 0, 0, 0, 0, 0};
        for (int k = 0; k < 256; ++k) {
            float ww = W2t[(size_t)k * 128 + tid];
#pragma unroll
            for (int r = 0; r < MR; ++r) acc[r] += h1s[r][k] * ww;
        }
        float bb = b2[tid];
#pragma unroll
        for (int r = 0; r < MR; ++r) h2s[r][tid] = fmaxf(acc[r] + bb, 0.f);
    }
    __syncthreads();
    {
        int r = tid >> 5, j = tid & 31;
        float p = 0.f;
#pragma unroll
        for (int m = 0; m < 4; ++m) p += h2s[r][j + 32 * m] * W3[j + 32 * m];
        p += __shfl_xor(p, 16);
        p += __shfl_xor(p, 8);
        p += __shfl_xor(p, 4);
        p += __shfl_xor(p, 2);
        p += __shfl_xor(p, 1);
        if (j == 0) out[b0 + r] = 1.f / (1.f + __expf(-(p + b3[0])));
    }
}

extern "C" void kernel_launch(void* const* d_in, const int* in_sizes, int n_in,
                              void* d_out, int out_size, void* d_ws, size_t ws_size,
                              hipStream_t stream) {
    const int* user_id = (const int*)d_in[0];
    const int* item_id = (const int*)d_in[1];
    const int* item_cat = (const int*)d_in[2];
    const int* item_dur = (const int*)d_in[3];
    const int* hseq = (const int*)d_in[4];
    const float* user_dense = (const float*)d_in[5];
    const float* item_dense = (const float*)d_in[6];
    const float* user_table = (const float*)d_in[7];
    const float* item_table = (const float*)d_in[8];
    const float* cat_table = (const float*)d_in[9];
    const float* dur_table = (const float*)d_in[10];
    const float* hist_table = (const float*)d_in[11];
    const float* projW = (const float*)d_in[12];
    const float* gWi = (const float*)d_in[13];
    const float* gWh = (const float*)d_in[14];
    const float* gbi = (const float*)d_in[15];
    const float* gbh = (const float*)d_in[16];
    const float* aWr = (const float*)d_in[17];
    const float* abr = (const float*)d_in[18];
    const float* aWu = (const float*)d_in[19];
    const float* abu = (const float*)d_in[20];
    const float* aWh = (const float*)d_in[21];
    const float* abh = (const float*)d_in[22];
    const float* mW1 = (const float*)d_in[23];
    const float* mb1 = (const float*)d_in[24];
    const float* mW2 = (const float*)d_in[25];
    const float* mb2 = (const float*)d_in[26];
    const float* mW3 = (const float*)d_in[27];
    const float* mb3 = (const float*)d_in[28];
    float* out = (float*)d_out;

    float* ws = (float*)d_ws;
    float* target = ws;                                     // 262144 f
    unsigned short* h_bf = (unsigned short*)(ws + 262144);  // 26214400 f-slots
    float* attn = ws + 262144 + 26214400;                   // 409600 f
    float* evolved = attn + 409600;                         // 262144 f
    float* W1t = evolved + 262144;                          // 84992 f
    float* W2t = W1t + 84992;                               // 32768 f
    unsigned short* hist_bf = (unsigned short*)(W2t + 32768);  // 6400064 f-slots

    const int n8 = 100001 * 16;  // (N_ITEMS+1)*128/8
    hipLaunchKernelGGL(cvt_hist, dim3((n8 + 255) / 256), dim3(256), 0, stream,
                       hist_table, hist_bf, n8);
    hipLaunchKernelGGL(transpose_kernel, dim3(332), dim3(256), 0, stream, mW1, W1t, 256, 332);
    hipLaunchKernelGGL(transpose_kernel, dim3(256), dim3(128), 0, stream, mW2, W2t, 128, 256);
    hipLaunchKernelGGL(target_kernel, dim3(2048), dim3(128), 0, stream,
                       item_id, item_table, projW, target);
    hipLaunchKernelGGL(gru_v4, dim3(BB / GR), dim3(512), 0, stream,
                       hseq, hist_bf, gWi, gWh, gbi, gbh, h_bf);
    hipLaunchKernelGGL(score_softmax, dim3(BB), dim3(256), 0, stream,
                       h_bf, target, hseq, attn);
    hipLaunchKernelGGL(augru_v4, dim3(BB / GR), dim3(512), 0, stream,
                       h_bf, attn, hseq, aWr, aWu, aWh, abr, abu, abh, evolved);
    hipLaunchKernelGGL(mlp_kernel, dim3(BB / MR), dim3(256), 0, stream,
                       user_id, item_id, item_cat, item_dur, user_dense, item_dense,
                       user_table, item_table, cat_table, dur_table, evolved,
                       W1t, mb1, W2t, mb2, mW3, mb3, out);
}